// Round 1
// baseline (562.005 us; speedup 1.0000x reference)
//
#include <hip/hip_runtime.h>
#include <stdint.h>

#define NTOK 131072
#define DIM  256
#define NE   8

typedef float  floatx4 __attribute__((ext_vector_type(4)));
typedef short  bhalf8  __attribute__((ext_vector_type(8)));

__device__ __forceinline__ unsigned short f2bf(float f) {
    union { float f; unsigned u; } v; v.f = f;
    unsigned u = v.u;
    unsigned r = (u + 0x7fffu + ((u >> 16) & 1u)) >> 16;
    return (unsigned short)r;
}

// ---------------------------------------------------------------------------
// K0: repack expert_w (fp32 [e][o][k]) -> bf16 in MFMA B-fragment order:
//     Wf[((e*8+ks)*16+ot)*64 + lane] is a 16B blob, bf16 j = W[e][ot*16+(lane&15)][ks*32+8*(lane>>4)+j]
// ---------------------------------------------------------------------------
__global__ __launch_bounds__(256) void k_wfrag(const float* __restrict__ W,
                                               unsigned short* __restrict__ Wf) {
    int tid  = blockIdx.x * 256 + threadIdx.x;   // 65536 threads
    int lane = tid & 63;
    int grp  = tid >> 6;                         // (e*8+ks)*16+ot, 0..1023
    int ot = grp & 15;
    int ks = (grp >> 4) & 7;
    int e  = grp >> 7;
    int o = ot * 16 + (lane & 15);
    int k = ks * 32 + 8 * (lane >> 4);
    const float* src = W + ((size_t)e * DIM + o) * DIM + k;
    unsigned short t[8];
#pragma unroll
    for (int j = 0; j < 8; j++) t[j] = f2bf(src[j]);
    uint4 u;
    u.x = (unsigned)t[0] | ((unsigned)t[1] << 16);
    u.y = (unsigned)t[2] | ((unsigned)t[3] << 16);
    u.z = (unsigned)t[4] | ((unsigned)t[5] << 16);
    u.w = (unsigned)t[6] | ((unsigned)t[7] << 16);
    ((uint4*)Wf)[(size_t)grp * 64 + lane] = u;
}

// ---------------------------------------------------------------------------
// K1: bias_proj[e][o] = sum_k bias[e][k] * W[e][o][k]   (fp32, one wave/output)
// ---------------------------------------------------------------------------
__global__ __launch_bounds__(256) void k_bproj(const float* __restrict__ W,
                                               const float* __restrict__ bias,
                                               float* __restrict__ bp) {
    int wid  = (blockIdx.x * 256 + threadIdx.x) >> 6;  // 0..2047
    int lane = threadIdx.x & 63;
    int e = wid >> 8;
    int o = wid & 255;
    const float* wr = W + ((size_t)e * DIM + o) * DIM;
    const float* br = bias + e * DIM;
    float s = 0.f;
#pragma unroll
    for (int k = 0; k < 4; k++) s += wr[lane + 64 * k] * br[lane + 64 * k];
#pragma unroll
    for (int m = 32; m; m >>= 1) s += __shfl_xor(s, m, 64);
    if (lane == 0) bp[e * DIM + o] = s;
}

// ---------------------------------------------------------------------------
// K2: gating. 8 threads per token, fp64 accumulation (fp32 products exact in
// fp64 -> matches a float64 numpy reference; avoids top-k flips on near-ties).
// Writes dense gate vector G[n][8] (zeros outside top-2). Stable top-2.
// ---------------------------------------------------------------------------
__global__ __launch_bounds__(256) void k_gate(const float* __restrict__ x,
                                              const float* __restrict__ wg,
                                              float* __restrict__ G,
                                              float* __restrict__ d_out,
                                              long long loss_idx) {
    int t   = threadIdx.x;
    int tok = blockIdx.x * 32 + (t >> 3);
    int q   = t & 7;

    const float4* xr = (const float4*)(x + (size_t)tok * DIM + q * 32);
    float xv[32];
#pragma unroll
    for (int i = 0; i < 8; i++) {
        float4 v = xr[i];
        xv[4 * i] = v.x; xv[4 * i + 1] = v.y; xv[4 * i + 2] = v.z; xv[4 * i + 3] = v.w;
    }
    double acc[NE];
#pragma unroll
    for (int e = 0; e < NE; e++) acc[e] = 0.0;

    const float4* wg4 = (const float4*)wg;   // w_gate[k][e], 8 floats per k
#pragma unroll
    for (int kk = 0; kk < 32; kk++) {
        int k = q * 32 + kk;
        float4 w0 = wg4[k * 2];
        float4 w1 = wg4[k * 2 + 1];
        double xd = (double)xv[kk];
        acc[0] += xd * (double)w0.x; acc[1] += xd * (double)w0.y;
        acc[2] += xd * (double)w0.z; acc[3] += xd * (double)w0.w;
        acc[4] += xd * (double)w1.x; acc[5] += xd * (double)w1.y;
        acc[6] += xd * (double)w1.z; acc[7] += xd * (double)w1.w;
    }
#pragma unroll
    for (int e = 0; e < NE; e++) {
        acc[e] += __shfl_xor(acc[e], 1, 64);
        acc[e] += __shfl_xor(acc[e], 2, 64);
        acc[e] += __shfl_xor(acc[e], 4, 64);
    }
    if (q == 0) {
        int i1 = 0; double v1 = acc[0];
#pragma unroll
        for (int e = 1; e < NE; e++) if (acc[e] > v1) { v1 = acc[e]; i1 = e; }
        int i2 = -1; double v2 = -1e300;
#pragma unroll
        for (int e = 0; e < NE; e++) if (e != i1 && acc[e] > v2) { v2 = acc[e]; i2 = e; }
        double ex  = exp(v2 - v1);          // <= 1
        double den = 1.0 + ex;
        float g1 = (float)(1.0 / den);
        float g2 = (float)(ex / den);
#pragma unroll
        for (int e = 0; e < NE; e++) {
            float gv = (e == i1) ? g1 : ((e == i2) ? g2 : 0.0f);
            G[(size_t)tok * NE + e] = gv;
        }
    }
    if (blockIdx.x == 0 && t == 0) d_out[loss_idx] = 0.0f;  // load_loss = 0
}

// ---------------------------------------------------------------------------
// K3: masked-dense MFMA: out[n][o] = sum_e g[n][e]*(x W_e^T)[n][o] - sum_e g[n][e]*bp[e][o]
// Block: 512 thr (8 waves, 2x4), tile M=64 tokens x N=256 outs, K=256, E=8.
// x tile bf16 in LDS, XOR-swizzled (byte ^= (row&7)<<4) to kill the
// row-major stride-512B 32-way bank conflict on ds_read_b128 (G4).
// W chunks reg-staged from fragment-ordered ws -> linear LDS, conflict-free reads.
// ---------------------------------------------------------------------------
__global__ __launch_bounds__(512, 4) void k_moe(const float* __restrict__ x,
                                                const unsigned short* __restrict__ Wf,
                                                const float* __restrict__ G,
                                                const float* __restrict__ bp,
                                                float* __restrict__ out) {
    __shared__ __align__(16) unsigned short xA[64 * 256];   // 32KB, swizzled
    __shared__ __align__(16) unsigned short wB[16 * 64 * 8]; // 16KB, frag order
    __shared__ float gS[64 * NE];                            // 2KB
    __shared__ float bpS[NE * 256];                          // 8KB

    int t    = threadIdx.x;
    int lane = t & 63;
    int wid  = t >> 6;          // 0..7
    int wm = wid >> 2;          // 0..1  (M)
    int wn = wid & 3;           // 0..3  (N)
    size_t base = (size_t)blockIdx.x * 64;

    // ---- stage x tile (fp32 coalesced -> bf16 swizzled LDS), gates, bias_proj
    {
        const float4* xg = (const float4*)(x + base * DIM);
#pragma unroll
        for (int i = 0; i < 8; i++) {
            int f4 = i * 512 + t;            // 0..4095, coalesced
            float4 v = xg[f4];
            int flat = f4 * 4;
            int row  = flat >> 8;
            int k    = flat & 255;
            unsigned short b0 = f2bf(v.x), b1 = f2bf(v.y), b2 = f2bf(v.z), b3 = f2bf(v.w);
            uint2 pk;
            pk.x = (unsigned)b0 | ((unsigned)b1 << 16);
            pk.y = (unsigned)b2 | ((unsigned)b3 << 16);
            int byte = row * 512 + k * 2;
            byte ^= (row & 7) << 4;
            *(uint2*)((char*)xA + byte) = pk;
        }
        gS[t] = G[base * NE + t];
#pragma unroll
        for (int i = 0; i < 4; i++) bpS[i * 512 + t] = bp[i * 512 + t];
    }
    __syncthreads();

    floatx4 zero = {0.f, 0.f, 0.f, 0.f};
    floatx4 accO[2][4];
#pragma unroll
    for (int mi = 0; mi < 2; mi++)
#pragma unroll
        for (int ni = 0; ni < 4; ni++) accO[mi][ni] = zero;

    int rlo = lane & 15;
    int kq  = lane >> 4;

    for (int e = 0; e < NE; e++) {
        floatx4 accE[2][4];
#pragma unroll
        for (int mi = 0; mi < 2; mi++)
#pragma unroll
            for (int ni = 0; ni < 4; ni++) accE[mi][ni] = zero;

        for (int ks = 0; ks < 8; ks++) {
            // issue global loads early (latency hides under the barrier wait)
            const uint4* wsrc = (const uint4*)Wf +
                (((size_t)(e * 8 + ks) * 16 + 2 * wid) * 64 + lane);
            uint4 wv0 = wsrc[0];
            uint4 wv1 = wsrc[64];
            __syncthreads();   // everyone done reading previous wB chunk
            *(uint4*)((char*)wB + ((2 * wid + 0) * 64 + lane) * 16) = wv0;
            *(uint4*)((char*)wB + ((2 * wid + 1) * 64 + lane) * 16) = wv1;
            __syncthreads();   // chunk visible

            bhalf8 a[2], b[4];
#pragma unroll
            for (int mi = 0; mi < 2; mi++) {
                int row = wm * 32 + mi * 16 + rlo;
                int abyte = row * 512 + ks * 64 + kq * 16;
                abyte ^= (row & 7) << 4;
                a[mi] = *(const bhalf8*)((const char*)xA + abyte);
            }
#pragma unroll
            for (int ni = 0; ni < 4; ni++) {
                int ot = wn * 4 + ni;
                b[ni] = *(const bhalf8*)((const char*)wB + (ot * 64 + lane) * 16);
            }
#pragma unroll
            for (int mi = 0; mi < 2; mi++)
#pragma unroll
                for (int ni = 0; ni < 4; ni++)
                    accE[mi][ni] = __builtin_amdgcn_mfma_f32_16x16x32_bf16(
                        a[mi], b[ni], accE[mi][ni], 0, 0, 0);
        }
        // fold this expert into the output accumulator, weighted by its gate
#pragma unroll
        for (int mi = 0; mi < 2; mi++)
#pragma unroll
            for (int r = 0; r < 4; r++) {
                int row = wm * 32 + mi * 16 + kq * 4 + r;
                float g = gS[row * NE + e];
#pragma unroll
                for (int ni = 0; ni < 4; ni++)
                    accO[mi][ni][r] += g * accE[mi][ni][r];
            }
    }

    // ---- epilogue: subtract gated bias_proj, store
#pragma unroll
    for (int mi = 0; mi < 2; mi++)
#pragma unroll
        for (int ni = 0; ni < 4; ni++) {
            int col = wn * 64 + ni * 16 + rlo;
#pragma unroll
            for (int r = 0; r < 4; r++) {
                int row = wm * 32 + mi * 16 + kq * 4 + r;
                float bsum = 0.f;
#pragma unroll
                for (int e = 0; e < NE; e++)
                    bsum += gS[row * NE + e] * bpS[e * 256 + col];
                out[(base + row) * DIM + col] = accO[mi][ni][r] - bsum;
            }
        }
}

// ---------------------------------------------------------------------------
extern "C" void kernel_launch(void* const* d_in, const int* in_sizes, int n_in,
                              void* d_out, int out_size, void* d_ws, size_t ws_size,
                              hipStream_t stream) {
    const float* x  = (const float*)d_in[0];   // [131072,256]
    const float* wg = (const float*)d_in[1];   // [256,8]
    const float* ew = (const float*)d_in[2];   // [8,256,256]
    const float* eb = (const float*)d_in[3];   // [8,256]
    float* out = (float*)d_out;                // [131072*256 + 1]

    // ws layout: Wf bf16 frag-ordered (2MB) | bp f32 (8KB) | G f32 (4MB)
    unsigned short* Wf = (unsigned short*)d_ws;
    float* bp = (float*)((char*)d_ws + (size_t)2 * 1024 * 1024);
    float* G  = (float*)((char*)d_ws + (size_t)2 * 1024 * 1024 + 8192);

    k_wfrag<<<256, 256, 0, stream>>>(ew, Wf);
    k_bproj<<<512, 256, 0, stream>>>(ew, eb, bp);
    k_gate<<<NTOK / 32, 256, 0, stream>>>(x, wg, G, out, (long long)out_size - 1);
    k_moe<<<NTOK / 64, 512, 0, stream>>>(x, Wf, G, bp, out);
}

// Round 6
// 456.431 us; speedup vs baseline: 1.2313x; 1.2313x over previous
//
#include <hip/hip_runtime.h>
#include <stdint.h>

#define NTOK 131072
#define DIM  256
#define NE   8
#define MAXT 2112   // 2048 data tiles + 64 pad tiles max

typedef float  floatx4 __attribute__((ext_vector_type(4)));
typedef short  bhalf8  __attribute__((ext_vector_type(8)));

__device__ __forceinline__ unsigned short f2bf(float f) {
    union { float f; unsigned u; } v; v.f = f;
    unsigned u = v.u;
    return (unsigned short)((u + 0x7fffu + ((u >> 16) & 1u)) >> 16);
}

// ---------------------------------------------------------------------------
// K0: repack expert_w (fp32 [e][o][k]) -> bf16 MFMA B-fragment order.
// Wf[((e*8+ks)*16+ot)*64+lane] (16B): bf16 j = W[e][ot*16+(lane&15)][ks*32+8*(lane>>4)+j]
// ---------------------------------------------------------------------------
__global__ __launch_bounds__(256) void k_wfrag(const float* __restrict__ W,
                                               unsigned short* __restrict__ Wf) {
    int tid  = blockIdx.x * 256 + threadIdx.x;
    int lane = tid & 63;
    int grp  = tid >> 6;                 // 0..1023
    int ot = grp & 15, ks = (grp >> 4) & 7, e = grp >> 7;
    int o = ot * 16 + (lane & 15);
    int k = ks * 32 + 8 * (lane >> 4);
    const float* src = W + ((size_t)e * DIM + o) * DIM + k;
    unsigned short t[8];
#pragma unroll
    for (int j = 0; j < 8; j++) t[j] = f2bf(src[j]);
    uint4 u;
    u.x = (unsigned)t[0] | ((unsigned)t[1] << 16);
    u.y = (unsigned)t[2] | ((unsigned)t[3] << 16);
    u.z = (unsigned)t[4] | ((unsigned)t[5] << 16);
    u.w = (unsigned)t[6] | ((unsigned)t[7] << 16);
    ((uint4*)Wf)[(size_t)grp * 64 + lane] = u;
}

// ---------------------------------------------------------------------------
// K1: bias_proj[e][o] = sum_k bias[e][k]*W[e][o][k]  (fp32)
// ---------------------------------------------------------------------------
__global__ __launch_bounds__(256) void k_bproj(const float* __restrict__ W,
                                               const float* __restrict__ bias,
                                               float* __restrict__ bp) {
    int wid  = (blockIdx.x * 256 + threadIdx.x) >> 6;
    int lane = threadIdx.x & 63;
    int e = wid >> 8, o = wid & 255;
    const float* wr = W + ((size_t)e * DIM + o) * DIM;
    const float* br = bias + e * DIM;
    float s = 0.f;
#pragma unroll
    for (int k = 0; k < 4; k++) s += wr[lane + 64 * k] * br[lane + 64 * k];
#pragma unroll
    for (int m = 32; m; m >>= 1) s += __shfl_xor(s, m, 64);
    if (lane == 0) bp[e * DIM + o] = s;
}

// ---------------------------------------------------------------------------
// K2: gating (fp64 accum -> top-k matches fp64 numpy ref). Emits per-token
// (g1,g2) and pair id p = argmax*8 + second. Zeroes load_loss.
// ---------------------------------------------------------------------------
__global__ __launch_bounds__(256) void k_gate2(const float* __restrict__ x,
                                               const float* __restrict__ wg,
                                               float2* __restrict__ G2,
                                               int* __restrict__ pairT,
                                               float* __restrict__ d_out,
                                               long long loss_idx) {
    int t   = threadIdx.x;
    int tok = blockIdx.x * 32 + (t >> 3);
    int q   = t & 7;

    const float4* xr = (const float4*)(x + (size_t)tok * DIM + q * 32);
    float xv[32];
#pragma unroll
    for (int i = 0; i < 8; i++) {
        float4 v = xr[i];
        xv[4*i] = v.x; xv[4*i+1] = v.y; xv[4*i+2] = v.z; xv[4*i+3] = v.w;
    }
    double acc[NE];
#pragma unroll
    for (int e = 0; e < NE; e++) acc[e] = 0.0;
    const float4* wg4 = (const float4*)wg;
#pragma unroll
    for (int kk = 0; kk < 32; kk++) {
        int k = q * 32 + kk;
        float4 w0 = wg4[k * 2];
        float4 w1 = wg4[k * 2 + 1];
        double xd = (double)xv[kk];
        acc[0] += xd * (double)w0.x; acc[1] += xd * (double)w0.y;
        acc[2] += xd * (double)w0.z; acc[3] += xd * (double)w0.w;
        acc[4] += xd * (double)w1.x; acc[5] += xd * (double)w1.y;
        acc[6] += xd * (double)w1.z; acc[7] += xd * (double)w1.w;
    }
#pragma unroll
    for (int e = 0; e < NE; e++) {
        acc[e] += __shfl_xor(acc[e], 1, 64);
        acc[e] += __shfl_xor(acc[e], 2, 64);
        acc[e] += __shfl_xor(acc[e], 4, 64);
    }
    if (q == 0) {
        int i1 = 0; double v1 = acc[0];
#pragma unroll
        for (int e = 1; e < NE; e++) if (acc[e] > v1) { v1 = acc[e]; i1 = e; }
        int i2 = -1; double v2 = -1e300;
#pragma unroll
        for (int e = 0; e < NE; e++) if (e != i1 && acc[e] > v2) { v2 = acc[e]; i2 = e; }
        double ex  = exp(v2 - v1);
        double den = 1.0 + ex;
        float2 g; g.x = (float)(1.0 / den); g.y = (float)(ex / den);
        G2[tok] = g;
        pairT[tok] = i1 * 8 + i2;
    }
    if (blockIdx.x == 0 && t == 0) d_out[loss_idx] = 0.0f;
}

// ---------------------------------------------------------------------------
// K3: histogram of pair ids. 64 blocks x 2048 tokens -> bhist[blk][64]
// ---------------------------------------------------------------------------
__global__ __launch_bounds__(256) void k_hist(const int* __restrict__ pairT,
                                              int* __restrict__ bhist) {
    __shared__ int h[64];
    int t = threadIdx.x;
    if (t < 64) h[t] = 0;
    __syncthreads();
    int base = blockIdx.x * 2048;
#pragma unroll
    for (int i = 0; i < 8; i++) atomicAdd(&h[pairT[base + i * 256 + t]], 1);
    __syncthreads();
    if (t < 64) bhist[blockIdx.x * 64 + t] = h[t];
}

// ---------------------------------------------------------------------------
// K4: scan. bhist -> per-(block,bin) exclusive offsets (in place), padded bin
// bases Pg[64] (multiples of 64), tilePair[MAXT] (-1 for unused tiles).
// ---------------------------------------------------------------------------
__global__ __launch_bounds__(256) void k_scan(int* __restrict__ bhist,
                                              int* __restrict__ Pg,
                                              int* __restrict__ tilePair) {
    __shared__ int sh[64 * 64];
    __shared__ int tot[64];
    int t = threadIdx.x;
    for (int i = t; i < 4096; i += 256) sh[i] = bhist[i];
    for (int i = t; i < MAXT; i += 256) tilePair[i] = -1;
    __syncthreads();
    if (t < 64) {
        int run = 0;
        for (int b = 0; b < 64; b++) { int v = sh[b * 64 + t]; sh[b * 64 + t] = run; run += v; }
        tot[t] = run;
    }
    __syncthreads();
    if (t == 0) {
        int pos = 0, tile = 0;
        for (int b = 0; b < 64; b++) {
            Pg[b] = pos;
            int nt = (tot[b] + 63) >> 6;
            for (int k = 0; k < nt; k++) tilePair[tile++] = b;
            pos += nt * 64;
        }
    }
    __syncthreads();
    for (int i = t; i < 4096; i += 256) bhist[i] = sh[i];
}

// ---------------------------------------------------------------------------
// K5: order[] = -1 (pad slots stay -1)
// ---------------------------------------------------------------------------
__global__ __launch_bounds__(256) void k_initord(int* __restrict__ order) {
    int i = blockIdx.x * 256 + threadIdx.x;
    if (i < MAXT * 64) order[i] = -1;
}

// ---------------------------------------------------------------------------
// K6: scatter token ids into pair-sorted order[] (LDS cursors only).
// ---------------------------------------------------------------------------
__global__ __launch_bounds__(256) void k_scatter(const int* __restrict__ pairT,
                                                 const int* __restrict__ bhist,
                                                 const int* __restrict__ Pg,
                                                 int* __restrict__ order) {
    __shared__ int cur[64];
    int t = threadIdx.x;
    if (t < 64) cur[t] = Pg[t] + bhist[blockIdx.x * 64 + t];
    __syncthreads();
    int base = blockIdx.x * 2048;
#pragma unroll
    for (int i = 0; i < 8; i++) {
        int tok = base + i * 256 + t;
        int p = pairT[tok];
        int pos = atomicAdd(&cur[p], 1);
        order[pos] = tok;
    }
}

// ---------------------------------------------------------------------------
// K7: pair-sorted MoE GEMM. One tile = 64 tokens sharing expert pair (eA,eB).
// 8 waves (2M x 4N). W: 16 chunks of 16KB double-buffered via global_load_lds,
// B-frags register-prefetched (1 full compute phase of load latency hiding).
// x tile bf16 in LDS, XOR-swizzled. Epilogue: LDS transpose -> float4 row
// stores (full 1KB rows) scattered by token.
// ---------------------------------------------------------------------------
__device__ __forceinline__ void stage_chunk(const unsigned short* Wf, char* wB,
                                            int buf, int chunk, int wid, int lane) {
    const char* g = (const char*)Wf + (size_t)chunk * 16384;
    char* l = wB + buf * 16384;
#pragma unroll
    for (int s = 0; s < 2; s++) {
        int off = s * 8192 + wid * 1024;
        __builtin_amdgcn_global_load_lds(
            (const __attribute__((address_space(1))) void*)(g + off + lane * 16),
            (__attribute__((address_space(3))) void*)(l + off), 16, 0, 0);
    }
}

__global__ __launch_bounds__(512, 4) void k_moe2(const float* __restrict__ x,
                                                 const unsigned short* __restrict__ Wf,
                                                 const float2* __restrict__ G2,
                                                 const float* __restrict__ bp,
                                                 const int* __restrict__ tilePair,
                                                 const int* __restrict__ order,
                                                 float* __restrict__ out) {
    __shared__ __align__(16) char smem[32768 + 2 * 16384];  // xA | wB0 | wB1 ; epilogue ot aliases [0,33280)
    __shared__ int   oS[64];
    __shared__ float gS1[64], gS2[64];

    int p = tilePair[blockIdx.x];
    if (p < 0) return;
    int eA = p >> 3, eB = p & 7;

    int t = threadIdx.x, lane = t & 63, wid = t >> 6;
    int wm = wid >> 2, wn = wid & 3;           // 2 x 4 wave grid
    int rlo = lane & 15, kq = lane >> 4;

    unsigned short* xA = (unsigned short*)smem;
    char* wB = smem + 32768;

    if (t < 64) oS[t] = order[blockIdx.x * 64 + t];
    __syncthreads();
    if (t < 64) {
        int tok = oS[t];
        float2 g = tok >= 0 ? G2[tok] : float2{0.f, 0.f};
        gS1[t] = g.x; gS2[t] = g.y;
    }
    // gather x rows (1KB contiguous per wave), cvt bf16, swizzled LDS write
    const float4* xg = (const float4*)x;
#pragma unroll
    for (int i = 0; i < 8; i++) {
        int f4 = i * 512 + t;
        int row = f4 >> 6, c4 = f4 & 63;
        int tok = oS[row];
        float4 v = {0.f, 0.f, 0.f, 0.f};
        if (tok >= 0) v = xg[(size_t)tok * 64 + c4];
        uint2 pk;
        pk.x = (unsigned)f2bf(v.x) | ((unsigned)f2bf(v.y) << 16);
        pk.y = (unsigned)f2bf(v.z) | ((unsigned)f2bf(v.w) << 16);
        int byte = (row * 512 + c4 * 8) ^ ((row & 7) << 4);
        *(uint2*)((char*)xA + byte) = pk;
    }
    stage_chunk(Wf, wB, 0, eA * 8, wid, lane);
    __syncthreads();                      // xA ready + chunk0 in wB0 (vmcnt drained)

    floatx4 zero = {0.f, 0.f, 0.f, 0.f};
    floatx4 accO[2][4], accE[2][4];
#pragma unroll
    for (int mi = 0; mi < 2; mi++)
#pragma unroll
        for (int ni = 0; ni < 4; ni++) { accO[mi][ni] = zero; accE[mi][ni] = zero; }

    bhalf8 breg[4];
#pragma unroll
    for (int ni = 0; ni < 4; ni++)
        breg[ni] = *(const bhalf8*)(wB + ((wn * 4 + ni) * 64 + lane) * 16);

#pragma unroll 2
    for (int c = 0; c < 16; c++) {
        int ks = c & 7;
        __syncthreads();                  // all waves done ds_reading chunk c's frags
        if (c + 1 < 16) {
            int cn = c + 1;
            int en = (cn >> 3) ? eB : eA;
            stage_chunk(Wf, wB, cn & 1, en * 8 + (cn & 7), wid, lane);
        }
        bhalf8 a[2];
#pragma unroll
        for (int mi = 0; mi < 2; mi++) {
            int row = wm * 32 + mi * 16 + rlo;
            int ab = (row * 512 + ks * 64 + kq * 16) ^ ((row & 7) << 4);
            a[mi] = *(const bhalf8*)((const char*)xA + ab);
        }
#pragma unroll
        for (int mi = 0; mi < 2; mi++)
#pragma unroll
            for (int ni = 0; ni < 4; ni++)
                accE[mi][ni] = __builtin_amdgcn_mfma_f32_16x16x32_bf16(
                    a[mi], breg[ni], accE[mi][ni], 0, 0, 0);
        if (ks == 7) {                    // fold expert into output acc, gated
            int second = c >> 3;
#pragma unroll
            for (int mi = 0; mi < 2; mi++)
#pragma unroll
                for (int r = 0; r < 4; r++) {
                    int row = wm * 32 + mi * 16 + kq * 4 + r;
                    float g = second ? gS2[row] : gS1[row];
#pragma unroll
                    for (int ni = 0; ni < 4; ni++) accO[mi][ni][r] += g * accE[mi][ni][r];
                }
#pragma unroll
            for (int mi = 0; mi < 2; mi++)
#pragma unroll
                for (int ni = 0; ni < 4; ni++) accE[mi][ni] = zero;
        }
        __syncthreads();                  // chunk c+1 written & visible
        if (c + 1 < 16) {
#pragma unroll
            for (int ni = 0; ni < 4; ni++)
                breg[ni] = *(const bhalf8*)(wB + ((c + 1) & 1) * 16384 +
                                            ((wn * 4 + ni) * 64 + lane) * 16);
        }
    }

    // ---- epilogue: LDS transpose (pitch 260 kills conflicts) -> float4 stores
    __syncthreads();
    float* ot = (float*)smem;             // 32 x 260 fp32, aliases xA (dead)
    const float4* bp4 = (const float4*)bp;
    int c4e = t & 63;
    float4 b1 = bp4[eA * 64 + c4e];
    float4 b2 = bp4[eB * 64 + c4e];
#pragma unroll
    for (int pass = 0; pass < 2; pass++) {
        if (wm == pass) {
#pragma unroll
            for (int mi = 0; mi < 2; mi++)
#pragma unroll
                for (int ni = 0; ni < 4; ni++) {
                    int col = wn * 64 + ni * 16 + rlo;
#pragma unroll
                    for (int r = 0; r < 4; r++) {
                        int lrow = mi * 16 + kq * 4 + r;
                        ot[lrow * 260 + col] = accO[mi][ni][r];
                    }
                }
        }
        __syncthreads();
#pragma unroll
        for (int i = 0; i < 4; i++) {
            int f4 = i * 512 + t;
            int lrow = f4 >> 6;
            int row = pass * 32 + lrow;
            int tok = oS[row];
            if (tok >= 0) {
                float4 v = *(const float4*)&ot[lrow * 260 + c4e * 4];
                float g1 = gS1[row], g2 = gS2[row];
                v.x -= g1 * b1.x + g2 * b2.x;
                v.y -= g1 * b1.y + g2 * b2.y;
                v.z -= g1 * b1.z + g2 * b2.z;
                v.w -= g1 * b1.w + g2 * b2.w;
                ((float4*)out)[(size_t)tok * 64 + c4e] = v;
            }
        }
        __syncthreads();
    }
}

// ---------------------------------------------------------------------------
extern "C" void kernel_launch(void* const* d_in, const int* in_sizes, int n_in,
                              void* d_out, int out_size, void* d_ws, size_t ws_size,
                              hipStream_t stream) {
    const float* x  = (const float*)d_in[0];
    const float* wg = (const float*)d_in[1];
    const float* ew = (const float*)d_in[2];
    const float* eb = (const float*)d_in[3];
    float* out = (float*)d_out;

    char* ws = (char*)d_ws;
    unsigned short* Wf  = (unsigned short*)(ws + 0);          // 2,097,152
    float*  bp   = (float*) (ws + 2097152);                   //     8,192
    float2* G2   = (float2*)(ws + 2105344);                   // 1,048,576
    int*    pairT= (int*)   (ws + 3153920);                   //   524,288
    int*    bhist= (int*)   (ws + 3678208);                   //    16,384
    int*    Pg   = (int*)   (ws + 3694592);                   //       256
    int*    tileP= (int*)   (ws + 3694848);                   //     8,448
    int*    order= (int*)   (ws + 3703296);                   //   540,672

    k_wfrag  <<<256, 256, 0, stream>>>(ew, Wf);
    k_bproj  <<<512, 256, 0, stream>>>(ew, eb, bp);
    k_gate2  <<<NTOK / 32, 256, 0, stream>>>(x, wg, G2, pairT, out, (long long)out_size - 1);
    k_hist   <<<64, 256, 0, stream>>>(pairT, bhist);
    k_scan   <<<1, 256, 0, stream>>>(bhist, Pg, tileP);
    k_initord<<<(MAXT * 64 + 255) / 256, 256, 0, stream>>>(order);
    k_scatter<<<64, 256, 0, stream>>>(pairT, bhist, Pg, order);
    k_moe2   <<<MAXT, 512, 0, stream>>>(x, Wf, G2, bp, tileP, order, out);
}

// Round 7
// 340.354 us; speedup vs baseline: 1.6512x; 1.3410x over previous
//
#include <hip/hip_runtime.h>
#include <stdint.h>

#define NTOK 131072
#define DIM  256
#define NE   8
#define MAXT 2112   // 2048 data tiles + 64 pad tiles max

typedef float  floatx4 __attribute__((ext_vector_type(4)));
typedef short  bhalf8  __attribute__((ext_vector_type(8)));

__device__ __forceinline__ unsigned short f2bf(float f) {
    union { float f; unsigned u; } v; v.f = f;
    unsigned u = v.u;
    return (unsigned short)((u + 0x7fffu + ((u >> 16) & 1u)) >> 16);
}

// ---------------------------------------------------------------------------
// K0: repack expert_w (fp32 [e][o][k]) -> bf16 MFMA B-fragment order.
// ---------------------------------------------------------------------------
__global__ __launch_bounds__(256) void k_wfrag(const float* __restrict__ W,
                                               unsigned short* __restrict__ Wf) {
    int tid  = blockIdx.x * 256 + threadIdx.x;
    int lane = tid & 63;
    int grp  = tid >> 6;                 // 0..1023
    int ot = grp & 15, ks = (grp >> 4) & 7, e = grp >> 7;
    int o = ot * 16 + (lane & 15);
    int k = ks * 32 + 8 * (lane >> 4);
    const float* src = W + ((size_t)e * DIM + o) * DIM + k;
    unsigned short t[8];
#pragma unroll
    for (int j = 0; j < 8; j++) t[j] = f2bf(src[j]);
    uint4 u;
    u.x = (unsigned)t[0] | ((unsigned)t[1] << 16);
    u.y = (unsigned)t[2] | ((unsigned)t[3] << 16);
    u.z = (unsigned)t[4] | ((unsigned)t[5] << 16);
    u.w = (unsigned)t[6] | ((unsigned)t[7] << 16);
    ((uint4*)Wf)[(size_t)grp * 64 + lane] = u;
}

// ---------------------------------------------------------------------------
// K1: bias_proj[e][o] = sum_k bias[e][k]*W[e][o][k]  (fp32)
// ---------------------------------------------------------------------------
__global__ __launch_bounds__(256) void k_bproj(const float* __restrict__ W,
                                               const float* __restrict__ bias,
                                               float* __restrict__ bp) {
    int wid  = (blockIdx.x * 256 + threadIdx.x) >> 6;
    int lane = threadIdx.x & 63;
    int e = wid >> 8, o = wid & 255;
    const float* wr = W + ((size_t)e * DIM + o) * DIM;
    const float* br = bias + e * DIM;
    float s = 0.f;
#pragma unroll
    for (int k = 0; k < 4; k++) s += wr[lane + 64 * k] * br[lane + 64 * k];
#pragma unroll
    for (int m = 32; m; m >>= 1) s += __shfl_xor(s, m, 64);
    if (lane == 0) bp[e * DIM + o] = s;
}

// ---------------------------------------------------------------------------
// K2 v2: gating with wg staged in LDS (fp64 accum for ranking fidelity).
// wg replicated per q-slice at stride 260 floats (260%32==4 -> the 8
// broadcast groups land on disjoint bank quads: conflict-free ds_read_b128).
// Was: wg re-read from L2 inside the FMA loop -> ~200cy serial stall/iter.
// ---------------------------------------------------------------------------
__global__ __launch_bounds__(256) void k_gate3(const float* __restrict__ x,
                                               const float* __restrict__ wg,
                                               float2* __restrict__ G2,
                                               int* __restrict__ pairT,
                                               float* __restrict__ d_out,
                                               long long loss_idx) {
    __shared__ float wgS[8 * 260];       // 8320 B
    int t = threadIdx.x;
    {
        int q = t >> 5, kk = t & 31;     // one (q,kk) per thread
        const float4* src = (const float4*)(wg + (q * 32 + kk) * 8);
        float4 a = src[0], b = src[1];
        float* dst = &wgS[q * 260 + kk * 8];
        *(float4*)dst = a;
        *(float4*)(dst + 4) = b;
    }
    int tok = blockIdx.x * 32 + (t >> 3);
    int q   = t & 7;

    const float4* xr = (const float4*)(x + (size_t)tok * DIM + q * 32);
    float xv[32];
#pragma unroll
    for (int i = 0; i < 8; i++) {
        float4 v = xr[i];
        xv[4*i] = v.x; xv[4*i+1] = v.y; xv[4*i+2] = v.z; xv[4*i+3] = v.w;
    }
    __syncthreads();

    double acc[NE];
#pragma unroll
    for (int e = 0; e < NE; e++) acc[e] = 0.0;
    const float* wrow = &wgS[q * 260];
#pragma unroll
    for (int kk = 0; kk < 32; kk++) {
        float4 w0 = *(const float4*)(wrow + kk * 8);
        float4 w1 = *(const float4*)(wrow + kk * 8 + 4);
        double xd = (double)xv[kk];
        acc[0] += xd * (double)w0.x; acc[1] += xd * (double)w0.y;
        acc[2] += xd * (double)w0.z; acc[3] += xd * (double)w0.w;
        acc[4] += xd * (double)w1.x; acc[5] += xd * (double)w1.y;
        acc[6] += xd * (double)w1.z; acc[7] += xd * (double)w1.w;
    }
#pragma unroll
    for (int e = 0; e < NE; e++) {
        acc[e] += __shfl_xor(acc[e], 1, 64);
        acc[e] += __shfl_xor(acc[e], 2, 64);
        acc[e] += __shfl_xor(acc[e], 4, 64);
    }
    if (q == 0) {
        int i1 = 0; double v1 = acc[0];
#pragma unroll
        for (int e = 1; e < NE; e++) if (acc[e] > v1) { v1 = acc[e]; i1 = e; }
        int i2 = -1; double v2 = -1e300;
#pragma unroll
        for (int e = 0; e < NE; e++) if (e != i1 && acc[e] > v2) { v2 = acc[e]; i2 = e; }
        double ex  = exp(v2 - v1);
        double den = 1.0 + ex;
        float2 g; g.x = (float)(1.0 / den); g.y = (float)(ex / den);
        G2[tok] = g;
        pairT[tok] = i1 * 8 + i2;
    }
    if (blockIdx.x == 0 && t == 0) d_out[loss_idx] = 0.0f;
}

// ---------------------------------------------------------------------------
// K3: histogram of pair ids. 64 blocks x 2048 tokens -> bhist[blk][64]
// ---------------------------------------------------------------------------
__global__ __launch_bounds__(256) void k_hist(const int* __restrict__ pairT,
                                              int* __restrict__ bhist) {
    __shared__ int h[64];
    int t = threadIdx.x;
    if (t < 64) h[t] = 0;
    __syncthreads();
    int base = blockIdx.x * 2048;
#pragma unroll
    for (int i = 0; i < 8; i++) atomicAdd(&h[pairT[base + i * 256 + t]], 1);
    __syncthreads();
    if (t < 64) bhist[blockIdx.x * 64 + t] = h[t];
}

// ---------------------------------------------------------------------------
// K4 v2: scan, fully parallel. Column-scan per bin (64 lanes x 64 iters),
// wave prefix-scan (shfl_up) for padded bases, binary-search tile fill.
// Was: single-lane serial loop writing ~2112 tilePair entries.
// ---------------------------------------------------------------------------
__global__ __launch_bounds__(256) void k_scan(int* __restrict__ bhist,
                                              int* __restrict__ Pg,
                                              int* __restrict__ tilePair) {
    __shared__ int sh[64 * 64];
    __shared__ int cnt[65];              // exclusive tile-count prefix
    int t = threadIdx.x;
    for (int i = t; i < 4096; i += 256) sh[i] = bhist[i];
    __syncthreads();
    int nt = 0;
    if (t < 64) {
        int run = 0;
        for (int b = 0; b < 64; b++) { int v = sh[b * 64 + t]; sh[b * 64 + t] = run; run += v; }
        nt = (run + 63) >> 6;            // tiles for bin t
        int pref = nt;                   // inclusive prefix over 64 lanes
#pragma unroll
        for (int d = 1; d < 64; d <<= 1) {
            int o = __shfl_up(pref, d, 64);
            if (t >= d) pref += o;
        }
        cnt[t + 1] = pref;
        if (t == 0) cnt[0] = 0;
        Pg[t] = (pref - nt) * 64;
    }
    __syncthreads();
    int T = cnt[64];
    for (int i = t; i < MAXT; i += 256) {
        int pv = -1;
        if (i < T) {                     // largest b with cnt[b] <= i
            int lo = 0, hi = 64;
            while (hi - lo > 1) { int mid = (lo + hi) >> 1; if (cnt[mid] <= i) lo = mid; else hi = mid; }
            pv = lo;
        }
        tilePair[i] = pv;
    }
    __syncthreads();
    for (int i = t; i < 4096; i += 256) bhist[i] = sh[i];
}

// ---------------------------------------------------------------------------
// K5: order[] = -1 (pad slots stay -1)
// ---------------------------------------------------------------------------
__global__ __launch_bounds__(256) void k_initord(int* __restrict__ order) {
    int i = blockIdx.x * 256 + threadIdx.x;
    if (i < MAXT * 64) order[i] = -1;
}

// ---------------------------------------------------------------------------
// K6: scatter token ids into pair-sorted order[] (LDS cursors only).
// ---------------------------------------------------------------------------
__global__ __launch_bounds__(256) void k_scatter(const int* __restrict__ pairT,
                                                 const int* __restrict__ bhist,
                                                 const int* __restrict__ Pg,
                                                 int* __restrict__ order) {
    __shared__ int cur[64];
    int t = threadIdx.x;
    if (t < 64) cur[t] = Pg[t] + bhist[blockIdx.x * 64 + t];
    __syncthreads();
    int base = blockIdx.x * 2048;
#pragma unroll
    for (int i = 0; i < 8; i++) {
        int tok = base + i * 256 + t;
        int p = pairT[tok];
        int pos = atomicAdd(&cur[p], 1);
        order[pos] = tok;
    }
}

// ---------------------------------------------------------------------------
// K7: pair-sorted MoE GEMM (unchanged from R2 design).
// ---------------------------------------------------------------------------
__device__ __forceinline__ void stage_chunk(const unsigned short* Wf, char* wB,
                                            int buf, int chunk, int wid, int lane) {
    const char* g = (const char*)Wf + (size_t)chunk * 16384;
    char* l = wB + buf * 16384;
#pragma unroll
    for (int s = 0; s < 2; s++) {
        int off = s * 8192 + wid * 1024;
        __builtin_amdgcn_global_load_lds(
            (const __attribute__((address_space(1))) void*)(g + off + lane * 16),
            (__attribute__((address_space(3))) void*)(l + off), 16, 0, 0);
    }
}

__global__ __launch_bounds__(512, 4) void k_moe2(const float* __restrict__ x,
                                                 const unsigned short* __restrict__ Wf,
                                                 const float2* __restrict__ G2,
                                                 const float* __restrict__ bp,
                                                 const int* __restrict__ tilePair,
                                                 const int* __restrict__ order,
                                                 float* __restrict__ out) {
    __shared__ __align__(16) char smem[32768 + 2 * 16384];
    __shared__ int   oS[64];
    __shared__ float gS1[64], gS2[64];

    int p = tilePair[blockIdx.x];
    if (p < 0) return;
    int eA = p >> 3, eB = p & 7;

    int t = threadIdx.x, lane = t & 63, wid = t >> 6;
    int wm = wid >> 2, wn = wid & 3;
    int rlo = lane & 15, kq = lane >> 4;

    unsigned short* xA = (unsigned short*)smem;
    char* wB = smem + 32768;

    if (t < 64) oS[t] = order[blockIdx.x * 64 + t];
    __syncthreads();
    if (t < 64) {
        int tok = oS[t];
        float2 g = tok >= 0 ? G2[tok] : float2{0.f, 0.f};
        gS1[t] = g.x; gS2[t] = g.y;
    }
    const float4* xg = (const float4*)x;
#pragma unroll
    for (int i = 0; i < 8; i++) {
        int f4 = i * 512 + t;
        int row = f4 >> 6, c4 = f4 & 63;
        int tok = oS[row];
        float4 v = {0.f, 0.f, 0.f, 0.f};
        if (tok >= 0) v = xg[(size_t)tok * 64 + c4];
        uint2 pk;
        pk.x = (unsigned)f2bf(v.x) | ((unsigned)f2bf(v.y) << 16);
        pk.y = (unsigned)f2bf(v.z) | ((unsigned)f2bf(v.w) << 16);
        int byte = (row * 512 + c4 * 8) ^ ((row & 7) << 4);
        *(uint2*)((char*)xA + byte) = pk;
    }
    stage_chunk(Wf, wB, 0, eA * 8, wid, lane);
    __syncthreads();

    floatx4 zero = {0.f, 0.f, 0.f, 0.f};
    floatx4 accO[2][4], accE[2][4];
#pragma unroll
    for (int mi = 0; mi < 2; mi++)
#pragma unroll
        for (int ni = 0; ni < 4; ni++) { accO[mi][ni] = zero; accE[mi][ni] = zero; }

    bhalf8 breg[4];
#pragma unroll
    for (int ni = 0; ni < 4; ni++)
        breg[ni] = *(const bhalf8*)(wB + ((wn * 4 + ni) * 64 + lane) * 16);

#pragma unroll 2
    for (int c = 0; c < 16; c++) {
        int ks = c & 7;
        __syncthreads();
        if (c + 1 < 16) {
            int cn = c + 1;
            int en = (cn >> 3) ? eB : eA;
            stage_chunk(Wf, wB, cn & 1, en * 8 + (cn & 7), wid, lane);
        }
        bhalf8 a[2];
#pragma unroll
        for (int mi = 0; mi < 2; mi++) {
            int row = wm * 32 + mi * 16 + rlo;
            int ab = (row * 512 + ks * 64 + kq * 16) ^ ((row & 7) << 4);
            a[mi] = *(const bhalf8*)((const char*)xA + ab);
        }
#pragma unroll
        for (int mi = 0; mi < 2; mi++)
#pragma unroll
            for (int ni = 0; ni < 4; ni++)
                accE[mi][ni] = __builtin_amdgcn_mfma_f32_16x16x32_bf16(
                    a[mi], breg[ni], accE[mi][ni], 0, 0, 0);
        if (ks == 7) {
            int second = c >> 3;
#pragma unroll
            for (int mi = 0; mi < 2; mi++)
#pragma unroll
                for (int r = 0; r < 4; r++) {
                    int row = wm * 32 + mi * 16 + kq * 4 + r;
                    float g = second ? gS2[row] : gS1[row];
#pragma unroll
                    for (int ni = 0; ni < 4; ni++) accO[mi][ni][r] += g * accE[mi][ni][r];
                }
#pragma unroll
            for (int mi = 0; mi < 2; mi++)
#pragma unroll
                for (int ni = 0; ni < 4; ni++) accE[mi][ni] = zero;
        }
        __syncthreads();
        if (c + 1 < 16) {
#pragma unroll
            for (int ni = 0; ni < 4; ni++)
                breg[ni] = *(const bhalf8*)(wB + ((c + 1) & 1) * 16384 +
                                            ((wn * 4 + ni) * 64 + lane) * 16);
        }
    }

    __syncthreads();
    float* ot = (float*)smem;
    const float4* bp4 = (const float4*)bp;
    int c4e = t & 63;
    float4 b1 = bp4[eA * 64 + c4e];
    float4 b2 = bp4[eB * 64 + c4e];
#pragma unroll
    for (int pass = 0; pass < 2; pass++) {
        if (wm == pass) {
#pragma unroll
            for (int mi = 0; mi < 2; mi++)
#pragma unroll
                for (int ni = 0; ni < 4; ni++) {
                    int col = wn * 64 + ni * 16 + rlo;
#pragma unroll
                    for (int r = 0; r < 4; r++) {
                        int lrow = mi * 16 + kq * 4 + r;
                        ot[lrow * 260 + col] = accO[mi][ni][r];
                    }
                }
        }
        __syncthreads();
#pragma unroll
        for (int i = 0; i < 4; i++) {
            int f4 = i * 512 + t;
            int lrow = f4 >> 6;
            int row = pass * 32 + lrow;
            int tok = oS[row];
            if (tok >= 0) {
                float4 v = *(const float4*)&ot[lrow * 260 + c4e * 4];
                float g1 = gS1[row], g2 = gS2[row];
                v.x -= g1 * b1.x + g2 * b2.x;
                v.y -= g1 * b1.y + g2 * b2.y;
                v.z -= g1 * b1.z + g2 * b2.z;
                v.w -= g1 * b1.w + g2 * b2.w;
                ((float4*)out)[(size_t)tok * 64 + c4e] = v;
            }
        }
        __syncthreads();
    }
}

// ---------------------------------------------------------------------------
extern "C" void kernel_launch(void* const* d_in, const int* in_sizes, int n_in,
                              void* d_out, int out_size, void* d_ws, size_t ws_size,
                              hipStream_t stream) {
    const float* x  = (const float*)d_in[0];
    const float* wg = (const float*)d_in[1];
    const float* ew = (const float*)d_in[2];
    const float* eb = (const float*)d_in[3];
    float* out = (float*)d_out;

    char* ws = (char*)d_ws;
    unsigned short* Wf  = (unsigned short*)(ws + 0);          // 2,097,152
    float*  bp   = (float*) (ws + 2097152);                   //     8,192
    float2* G2   = (float2*)(ws + 2105344);                   // 1,048,576
    int*    pairT= (int*)   (ws + 3153920);                   //   524,288
    int*    bhist= (int*)   (ws + 3678208);                   //    16,384
    int*    Pg   = (int*)   (ws + 3694592);                   //       256
    int*    tileP= (int*)   (ws + 3694848);                   //     8,448
    int*    order= (int*)   (ws + 3703296);                   //   540,672

    k_wfrag  <<<256, 256, 0, stream>>>(ew, Wf);
    k_bproj  <<<512, 256, 0, stream>>>(ew, eb, bp);
    k_gate3  <<<NTOK / 32, 256, 0, stream>>>(x, wg, G2, pairT, out, (long long)out_size - 1);
    k_hist   <<<64, 256, 0, stream>>>(pairT, bhist);
    k_scan   <<<1, 256, 0, stream>>>(bhist, Pg, tileP);
    k_initord<<<(MAXT * 64 + 255) / 256, 256, 0, stream>>>(order);
    k_scatter<<<64, 256, 0, stream>>>(pairT, bhist, Pg, order);
    k_moe2   <<<MAXT, 512, 0, stream>>>(x, Wf, G2, bp, tileP, order, out);
}

// Round 9
// 332.902 us; speedup vs baseline: 1.6882x; 1.0224x over previous
//
#include <hip/hip_runtime.h>
#include <stdint.h>

#define NTOK 131072
#define DIM  256
#define NE   8
#define MAXT 2112   // 2048 data tiles + 64 pad tiles max

typedef float  floatx4 __attribute__((ext_vector_type(4)));
typedef short  bhalf8  __attribute__((ext_vector_type(8)));

__device__ __forceinline__ unsigned short f2bf(float f) {
    union { float f; unsigned u; } v; v.f = f;
    unsigned u = v.u;
    return (unsigned short)((u + 0x7fffu + ((u >> 16) & 1u)) >> 16);
}

// ---------------------------------------------------------------------------
// K0: repack expert_w (fp32 [e][o][k]) -> bf16 MFMA B-fragment order.
// ---------------------------------------------------------------------------
__global__ __launch_bounds__(256) void k_wfrag(const float* __restrict__ W,
                                               unsigned short* __restrict__ Wf) {
    int tid  = blockIdx.x * 256 + threadIdx.x;
    int lane = tid & 63;
    int grp  = tid >> 6;                 // 0..1023
    int ot = grp & 15, ks = (grp >> 4) & 7, e = grp >> 7;
    int o = ot * 16 + (lane & 15);
    int k = ks * 32 + 8 * (lane >> 4);
    const float* src = W + ((size_t)e * DIM + o) * DIM + k;
    unsigned short t[8];
#pragma unroll
    for (int j = 0; j < 8; j++) t[j] = f2bf(src[j]);
    uint4 u;
    u.x = (unsigned)t[0] | ((unsigned)t[1] << 16);
    u.y = (unsigned)t[2] | ((unsigned)t[3] << 16);
    u.z = (unsigned)t[4] | ((unsigned)t[5] << 16);
    u.w = (unsigned)t[6] | ((unsigned)t[7] << 16);
    ((uint4*)Wf)[(size_t)grp * 64 + lane] = u;
}

// ---------------------------------------------------------------------------
// K1: bias_proj[e][o] = sum_k bias[e][k]*W[e][o][k]  (fp32)
// ---------------------------------------------------------------------------
__global__ __launch_bounds__(256) void k_bproj(const float* __restrict__ W,
                                               const float* __restrict__ bias,
                                               float* __restrict__ bp) {
    int wid  = (blockIdx.x * 256 + threadIdx.x) >> 6;
    int lane = threadIdx.x & 63;
    int e = wid >> 8, o = wid & 255;
    const float* wr = W + ((size_t)e * DIM + o) * DIM;
    const float* br = bias + e * DIM;
    float s = 0.f;
#pragma unroll
    for (int k = 0; k < 4; k++) s += wr[lane + 64 * k] * br[lane + 64 * k];
#pragma unroll
    for (int m = 32; m; m >>= 1) s += __shfl_xor(s, m, 64);
    if (lane == 0) bp[e * DIM + o] = s;
}

// ---------------------------------------------------------------------------
// K5 (runs early): order[] = -1, bhist[] = 0 (ws is poisoned 0xAA pre-launch)
// ---------------------------------------------------------------------------
__global__ __launch_bounds__(256) void k_initord(int* __restrict__ order,
                                                 int* __restrict__ bhist) {
    int i = blockIdx.x * 256 + threadIdx.x;
    if (i < MAXT * 64) order[i] = -1;
    if (i < 4096) bhist[i] = 0;
}

// ---------------------------------------------------------------------------
// K2 v3: gating with wg staged in LDS (fp64 accum for ranking fidelity)
// + fused pair-histogram (LDS bins -> 64 global atomics per block).
// ---------------------------------------------------------------------------
__global__ __launch_bounds__(256) void k_gate3(const float* __restrict__ x,
                                               const float* __restrict__ wg,
                                               float2* __restrict__ G2,
                                               int* __restrict__ pairT,
                                               int* __restrict__ bhist,
                                               float* __restrict__ d_out,
                                               long long loss_idx) {
    __shared__ float wgS[8 * 260];       // 8320 B, conflict-free replication
    __shared__ int h[64];
    int t = threadIdx.x;
    if (t < 64) h[t] = 0;
    {
        int q = t >> 5, kk = t & 31;     // one (q,kk) per thread
        const float4* src = (const float4*)(wg + (q * 32 + kk) * 8);
        float4 a = src[0], b = src[1];
        float* dst = &wgS[q * 260 + kk * 8];
        *(float4*)dst = a;
        *(float4*)(dst + 4) = b;
    }
    int tok = blockIdx.x * 32 + (t >> 3);
    int q   = t & 7;

    const float4* xr = (const float4*)(x + (size_t)tok * DIM + q * 32);
    float xv[32];
#pragma unroll
    for (int i = 0; i < 8; i++) {
        float4 v = xr[i];
        xv[4*i] = v.x; xv[4*i+1] = v.y; xv[4*i+2] = v.z; xv[4*i+3] = v.w;
    }
    __syncthreads();

    double acc[NE];
#pragma unroll
    for (int e = 0; e < NE; e++) acc[e] = 0.0;
    const float* wrow = &wgS[q * 260];
#pragma unroll
    for (int kk = 0; kk < 32; kk++) {
        float4 w0 = *(const float4*)(wrow + kk * 8);
        float4 w1 = *(const float4*)(wrow + kk * 8 + 4);
        double xd = (double)xv[kk];
        acc[0] += xd * (double)w0.x; acc[1] += xd * (double)w0.y;
        acc[2] += xd * (double)w0.z; acc[3] += xd * (double)w0.w;
        acc[4] += xd * (double)w1.x; acc[5] += xd * (double)w1.y;
        acc[6] += xd * (double)w1.z; acc[7] += xd * (double)w1.w;
    }
#pragma unroll
    for (int e = 0; e < NE; e++) {
        acc[e] += __shfl_xor(acc[e], 1, 64);
        acc[e] += __shfl_xor(acc[e], 2, 64);
        acc[e] += __shfl_xor(acc[e], 4, 64);
    }
    if (q == 0) {
        int i1 = 0; double v1 = acc[0];
#pragma unroll
        for (int e = 1; e < NE; e++) if (acc[e] > v1) { v1 = acc[e]; i1 = e; }
        int i2 = -1; double v2 = -1e300;
#pragma unroll
        for (int e = 0; e < NE; e++) if (e != i1 && acc[e] > v2) { v2 = acc[e]; i2 = e; }
        double ex  = exp(v2 - v1);
        double den = 1.0 + ex;
        float2 g; g.x = (float)(1.0 / den); g.y = (float)(ex / den);
        G2[tok] = g;
        int p = i1 * 8 + i2;
        pairT[tok] = p;
        atomicAdd(&h[p], 1);
    }
    __syncthreads();
    if (t < 64 && h[t]) atomicAdd(&bhist[(blockIdx.x >> 6) * 64 + t], h[t]);
    if (blockIdx.x == 0 && t == 0) d_out[loss_idx] = 0.0f;
}

// ---------------------------------------------------------------------------
// K4: scan, fully parallel (column scan + shfl_up prefix + binary-search fill)
// ---------------------------------------------------------------------------
__global__ __launch_bounds__(256) void k_scan(int* __restrict__ bhist,
                                              int* __restrict__ Pg,
                                              int* __restrict__ tilePair) {
    __shared__ int sh[64 * 64];
    __shared__ int cnt[65];              // exclusive tile-count prefix
    int t = threadIdx.x;
    for (int i = t; i < 4096; i += 256) sh[i] = bhist[i];
    __syncthreads();
    int nt = 0;
    if (t < 64) {
        int run = 0;
        for (int b = 0; b < 64; b++) { int v = sh[b * 64 + t]; sh[b * 64 + t] = run; run += v; }
        nt = (run + 63) >> 6;            // tiles for bin t
        int pref = nt;
#pragma unroll
        for (int d = 1; d < 64; d <<= 1) {
            int o = __shfl_up(pref, d, 64);
            if (t >= d) pref += o;
        }
        cnt[t + 1] = pref;
        if (t == 0) cnt[0] = 0;
        Pg[t] = (pref - nt) * 64;
    }
    __syncthreads();
    int T = cnt[64];
    for (int i = t; i < MAXT; i += 256) {
        int pv = -1;
        if (i < T) {                     // largest b with cnt[b] <= i
            int lo = 0, hi = 64;
            while (hi - lo > 1) { int mid = (lo + hi) >> 1; if (cnt[mid] <= i) lo = mid; else hi = mid; }
            pv = lo;
        }
        tilePair[i] = pv;
    }
    __syncthreads();
    for (int i = t; i < 4096; i += 256) bhist[i] = sh[i];
}

// ---------------------------------------------------------------------------
// K6: scatter token ids into pair-sorted order[] (LDS cursors only).
// ---------------------------------------------------------------------------
__global__ __launch_bounds__(256) void k_scatter(const int* __restrict__ pairT,
                                                 const int* __restrict__ bhist,
                                                 const int* __restrict__ Pg,
                                                 int* __restrict__ order) {
    __shared__ int cur[64];
    int t = threadIdx.x;
    if (t < 64) cur[t] = Pg[t] + bhist[blockIdx.x * 64 + t];
    __syncthreads();
    int base = blockIdx.x * 2048;
#pragma unroll
    for (int i = 0; i < 8; i++) {
        int tok = base + i * 256 + t;
        int p = pairT[tok];
        int pos = atomicAdd(&cur[p], 1);
        order[pos] = tok;
    }
}

// ---------------------------------------------------------------------------
// K7 v2: pair-sorted MoE GEMM, SINGLE barrier per chunk-step.
// Per step: issue stage(next chunk, buf^1) FIRST, then ds_read + 8 MFMA from
// buf (load latency hides under compute), then one __syncthreads (its
// implicit vmcnt(0) drains the stage). Was: 2 barriers/step + full-latency
// stall inside the barrier-to-barrier critical path.
// ---------------------------------------------------------------------------
__device__ __forceinline__ void stage_chunk(const unsigned short* Wf, char* wB,
                                            int buf, int chunk, int wid, int lane) {
    const char* g = (const char*)Wf + (size_t)chunk * 16384;
    char* l = wB + buf * 16384;
#pragma unroll
    for (int s = 0; s < 2; s++) {
        int off = s * 8192 + wid * 1024;
        __builtin_amdgcn_global_load_lds(
            (const __attribute__((address_space(1))) void*)(g + off + lane * 16),
            (__attribute__((address_space(3))) void*)(l + off), 16, 0, 0);
    }
}

__global__ __launch_bounds__(512, 4) void k_moe2(const float* __restrict__ x,
                                                 const unsigned short* __restrict__ Wf,
                                                 const float2* __restrict__ G2,
                                                 const float* __restrict__ bp,
                                                 const int* __restrict__ tilePair,
                                                 const int* __restrict__ order,
                                                 float* __restrict__ out) {
    __shared__ __align__(16) char smem[32768 + 2 * 16384];  // xA | wB0 | wB1
    __shared__ int   oS[64];
    __shared__ float gS1[64], gS2[64];

    int p = tilePair[blockIdx.x];
    if (p < 0) return;
    int eA = p >> 3, eB = p & 7;

    int t = threadIdx.x, lane = t & 63, wid = t >> 6;
    int wm = wid >> 2, wn = wid & 3;           // 2 x 4 wave grid
    int rlo = lane & 15, kq = lane >> 4;

    unsigned short* xA = (unsigned short*)smem;
    char* wB = smem + 32768;

    if (t < 64) oS[t] = order[blockIdx.x * 64 + t];
    __syncthreads();
    if (t < 64) {
        int tok = oS[t];
        float2 g = tok >= 0 ? G2[tok] : float2{0.f, 0.f};
        gS1[t] = g.x; gS2[t] = g.y;
    }
    // gather x rows (1KB contiguous per wave), cvt bf16, swizzled LDS write
    const float4* xg = (const float4*)x;
#pragma unroll
    for (int i = 0; i < 8; i++) {
        int f4 = i * 512 + t;
        int row = f4 >> 6, c4 = f4 & 63;
        int tok = oS[row];
        float4 v = {0.f, 0.f, 0.f, 0.f};
        if (tok >= 0) v = xg[(size_t)tok * 64 + c4];
        uint2 pk;
        pk.x = (unsigned)f2bf(v.x) | ((unsigned)f2bf(v.y) << 16);
        pk.y = (unsigned)f2bf(v.z) | ((unsigned)f2bf(v.w) << 16);
        int byte = (row * 512 + c4 * 8) ^ ((row & 7) << 4);
        *(uint2*)((char*)xA + byte) = pk;
    }
    stage_chunk(Wf, wB, 0, eA * 8, wid, lane);
    __syncthreads();                      // xA + chunk0 ready (vmcnt drained)

    floatx4 zero = {0.f, 0.f, 0.f, 0.f};
    floatx4 accO[2][4], accE[2][4];
#pragma unroll
    for (int mi = 0; mi < 2; mi++)
#pragma unroll
        for (int ni = 0; ni < 4; ni++) { accO[mi][ni] = zero; accE[mi][ni] = zero; }

    int cur = 0;
#pragma unroll 2
    for (int c = 0; c < 16; c++) {
        int ks = c & 7;
        if (c + 1 < 16) {                 // issue next-chunk loads FIRST
            int cn = c + 1;
            int en = (cn >> 3) ? eB : eA;
            stage_chunk(Wf, wB, cur ^ 1, en * 8 + (cn & 7), wid, lane);
        }
        bhalf8 a[2], b[4];
#pragma unroll
        for (int mi = 0; mi < 2; mi++) {
            int row = wm * 32 + mi * 16 + rlo;
            int ab = (row * 512 + ks * 64 + kq * 16) ^ ((row & 7) << 4);
            a[mi] = *(const bhalf8*)((const char*)xA + ab);
        }
#pragma unroll
        for (int ni = 0; ni < 4; ni++)
            b[ni] = *(const bhalf8*)(wB + cur * 16384 +
                                     ((wn * 4 + ni) * 64 + lane) * 16);
#pragma unroll
        for (int mi = 0; mi < 2; mi++)
#pragma unroll
            for (int ni = 0; ni < 4; ni++)
                accE[mi][ni] = __builtin_amdgcn_mfma_f32_16x16x32_bf16(
                    a[mi], b[ni], accE[mi][ni], 0, 0, 0);
        if (ks == 7) {                    // fold expert into output acc, gated
            int second = c >> 3;
#pragma unroll
            for (int mi = 0; mi < 2; mi++)
#pragma unroll
                for (int r = 0; r < 4; r++) {
                    int row = wm * 32 + mi * 16 + kq * 4 + r;
                    float g = second ? gS2[row] : gS1[row];
#pragma unroll
                    for (int ni = 0; ni < 4; ni++) accO[mi][ni][r] += g * accE[mi][ni][r];
                }
#pragma unroll
            for (int mi = 0; mi < 2; mi++)
#pragma unroll
                for (int ni = 0; ni < 4; ni++) accE[mi][ni] = zero;
        }
        __syncthreads();                  // one barrier/step: drains stage,
        cur ^= 1;                         // publishes buf for next step
    }

    // ---- epilogue: LDS transpose (pitch 260) -> float4 row stores
    float* ot = (float*)smem;             // 32 x 260 fp32, aliases xA (dead)
    const float4* bp4 = (const float4*)bp;
    int c4e = t & 63;
    float4 b1 = bp4[eA * 64 + c4e];
    float4 b2 = bp4[eB * 64 + c4e];
#pragma unroll
    for (int pass = 0; pass < 2; pass++) {
        if (wm == pass) {
#pragma unroll
            for (int mi = 0; mi < 2; mi++)
#pragma unroll
                for (int ni = 0; ni < 4; ni++) {
                    int col = wn * 64 + ni * 16 + rlo;
#pragma unroll
                    for (int r = 0; r < 4; r++) {
                        int lrow = mi * 16 + kq * 4 + r;
                        ot[lrow * 260 + col] = accO[mi][ni][r];
                    }
                }
        }
        __syncthreads();
#pragma unroll
        for (int i = 0; i < 4; i++) {
            int f4 = i * 512 + t;
            int lrow = f4 >> 6;
            int row = pass * 32 + lrow;
            int tok = oS[row];
            if (tok >= 0) {
                float4 v = *(const float4*)&ot[lrow * 260 + c4e * 4];
                float g1 = gS1[row], g2 = gS2[row];
                v.x -= g1 * b1.x + g2 * b2.x;
                v.y -= g1 * b1.y + g2 * b2.y;
                v.z -= g1 * b1.z + g2 * b2.z;
                v.w -= g1 * b1.w + g2 * b2.w;
                ((float4*)out)[(size_t)tok * 64 + c4e] = v;
            }
        }
        __syncthreads();
    }
}

// ---------------------------------------------------------------------------
extern "C" void kernel_launch(void* const* d_in, const int* in_sizes, int n_in,
                              void* d_out, int out_size, void* d_ws, size_t ws_size,
                              hipStream_t stream) {
    const float* x  = (const float*)d_in[0];
    const float* wg = (const float*)d_in[1];
    const float* ew = (const float*)d_in[2];
    const float* eb = (const float*)d_in[3];
    float* out = (float*)d_out;

    char* ws = (char*)d_ws;
    unsigned short* Wf  = (unsigned short*)(ws + 0);          // 2,097,152
    float*  bp   = (float*) (ws + 2097152);                   //     8,192
    float2* G2   = (float2*)(ws + 2105344);                   // 1,048,576
    int*    pairT= (int*)   (ws + 3153920);                   //   524,288
    int*    bhist= (int*)   (ws + 3678208);                   //    16,384
    int*    Pg   = (int*)   (ws + 3694592);                   //       256
    int*    tileP= (int*)   (ws + 3694848);                   //     8,448
    int*    order= (int*)   (ws + 3703296);                   //   540,672

    k_wfrag  <<<256, 256, 0, stream>>>(ew, Wf);
    k_bproj  <<<512, 256, 0, stream>>>(ew, eb, bp);
    k_initord<<<(MAXT * 64 + 255) / 256, 256, 0, stream>>>(order, bhist);
    k_gate3  <<<NTOK / 32, 256, 0, stream>>>(x, wg, G2, pairT, bhist, out,
                                             (long long)out_size - 1);
    k_scan   <<<1, 256, 0, stream>>>(bhist, Pg, tileP);
    k_scatter<<<64, 256, 0, stream>>>(pairT, bhist, Pg, order);
    k_moe2   <<<MAXT, 512, 0, stream>>>(x, Wf, G2, bp, tileP, order, out);
}